// Round 1
// baseline (731.981 us; speedup 1.0000x reference)
//
#include <hip/hip_runtime.h>
#include <math.h>

#define TT    4096      // T
#define TILE  32        // tokens per workgroup
#define NTILE 129       // ceil((T+1)/TILE)
#define PREC  516       // per-tile partial record: 4*128 P + 4 z
#define NB    64        // batch

// 100^(-i/7), i=0..7  (inverse timescales)
__device__ __constant__ float INV_TS[8] = {
    1.0f,                 0.5179474679231213f, 0.2682695795279726f, 0.1389495494373138f,
    0.0719685673001152f,  0.0372759372031494f, 0.0193069772888325f, 0.01f };

// ---------------- prep: demo encoder (blocks 0..63) + w_eff (block 64) ----------
__global__ __launch_bounds__(128) void prep_kernel(
    const float* __restrict__ demo,
    const float* __restrict__ dw1, const float* __restrict__ db1,
    const float* __restrict__ dw2, const float* __restrict__ db2,
    const float* __restrict__ W_k, const float* __restrict__ W_q,
    float* __restrict__ demo_enc, float* __restrict__ w_eff)
{
    const int b = blockIdx.x, tid = threadIdx.x;
    if (b < NB) {
        __shared__ float h[128];
        float a = db1[tid];
#pragma unroll
        for (int k = 0; k < 8; k++) a += demo[b*8 + k] * dw1[k*128 + tid];
        h[tid] = fmaxf(a, 0.f);
        __syncthreads();
        if (tid < 32) {
            float e = db2[tid];
            for (int k = 0; k < 128; k++) e += h[k] * dw2[k*32 + tid];
            demo_enc[b*32 + tid] = e;
        }
    } else {
        // w_eff[f][h] = (W_k[f, h*64:(h+1)*64] . W_q[h]) / 8,  f<32, h<4
        const int f = tid >> 2, hh = tid & 3;
        float s = 0.f;
        for (int d = 0; d < 64; d++) s += W_k[f*256 + hh*64 + d] * W_q[hh*64 + d];
        w_eff[f*4 + hh] = s * 0.125f;
    }
}

// ---------------- fused main helpers ----------------
__device__ __forceinline__ void gemm_k32(const float* __restrict__ w,
    const float* __restrict__ x0, const float* __restrict__ x1, float acc[2][8])
{
#pragma unroll
    for (int i = 0; i < 2; i++)
#pragma unroll
        for (int j = 0; j < 8; j++) acc[i][j] = 0.f;
#pragma unroll 4
    for (int k = 0; k < 32; k++) {
        float4 wa = *(const float4*)(w + k*128);
        float4 wb = *(const float4*)(w + k*128 + 4);
        float a = x0[k], c = x1[k];
        acc[0][0] += a*wa.x; acc[0][1] += a*wa.y; acc[0][2] += a*wa.z; acc[0][3] += a*wa.w;
        acc[0][4] += a*wb.x; acc[0][5] += a*wb.y; acc[0][6] += a*wb.z; acc[0][7] += a*wb.w;
        acc[1][0] += c*wa.x; acc[1][1] += c*wa.y; acc[1][2] += c*wa.z; acc[1][3] += c*wa.w;
        acc[1][4] += c*wb.x; acc[1][5] += c*wb.y; acc[1][6] += c*wb.z; acc[1][7] += c*wb.w;
    }
}

__device__ __forceinline__ void gemm_k128(const float* __restrict__ w,
    const float* __restrict__ x0, const float* __restrict__ x1, float acc[2][8])
{
#pragma unroll
    for (int i = 0; i < 2; i++)
#pragma unroll
        for (int j = 0; j < 8; j++) acc[i][j] = 0.f;
    for (int k = 0; k < 128; k += 4) {
        float4 a4 = *(const float4*)(x0 + k);
        float4 c4 = *(const float4*)(x1 + k);
#pragma unroll
        for (int kk = 0; kk < 4; kk++) {
            float4 wa = *(const float4*)(w + (k+kk)*128);
            float4 wb = *(const float4*)(w + (k+kk)*128 + 4);
            float a = ((const float*)&a4)[kk];
            float c = ((const float*)&c4)[kk];
            acc[0][0] += a*wa.x; acc[0][1] += a*wa.y; acc[0][2] += a*wa.z; acc[0][3] += a*wa.w;
            acc[0][4] += a*wb.x; acc[0][5] += a*wb.y; acc[0][6] += a*wb.z; acc[0][7] += a*wb.w;
            acc[1][0] += c*wa.x; acc[1][1] += c*wa.y; acc[1][2] += c*wa.z; acc[1][3] += c*wa.w;
            acc[1][4] += c*wb.x; acc[1][5] += c*wb.y; acc[1][6] += c*wb.z; acc[1][7] += c*wb.w;
        }
    }
}

__device__ __forceinline__ void bias_relu_store(float* __restrict__ dst /*[TILE][136]*/,
    float acc[2][8], const float* __restrict__ bias, int tj, int t0)
{
    float4 u = *(const float4*)(bias + tj*8);
    float4 v = *(const float4*)(bias + tj*8 + 4);
#pragma unroll
    for (int i = 0; i < 2; i++) {
        float4 o0, o1;
        o0.x = fmaxf(acc[i][0]+u.x, 0.f); o0.y = fmaxf(acc[i][1]+u.y, 0.f);
        o0.z = fmaxf(acc[i][2]+u.z, 0.f); o0.w = fmaxf(acc[i][3]+u.w, 0.f);
        o1.x = fmaxf(acc[i][4]+v.x, 0.f); o1.y = fmaxf(acc[i][5]+v.y, 0.f);
        o1.z = fmaxf(acc[i][6]+v.z, 0.f); o1.w = fmaxf(acc[i][7]+v.w, 0.f);
        float* row = dst + (size_t)(t0+i)*136 + tj*8;
        *(float4*)(row)     = o0;
        *(float4*)(row + 4) = o1;
    }
}

// ---------------- fused main: x-features -> phi MLP -> exp-weighted partials ----
__global__ __launch_bounds__(256) void fused_main(
    const float* __restrict__ times,  const float* __restrict__ values,
    const int*   __restrict__ meas,   const int*   __restrict__ lengths,
    const float* __restrict__ demo_enc, const float* __restrict__ w_eff,
    const float* __restrict__ w1, const float* __restrict__ b1,
    const float* __restrict__ w2, const float* __restrict__ b2,
    const float* __restrict__ w3, const float* __restrict__ b3,
    float* __restrict__ partials)
{
    __shared__ float Xs[TILE][33];          // padded stride 33
    __shared__ float Hbuf[2][TILE][136];    // padded stride 136 (16B aligned rows)
    __shared__ float wexp[TILE][4];

    const int tid  = threadIdx.x;
    const int b    = blockIdx.y;
    const int tile = blockIdx.x;
    const int g0   = tile * TILE;
    const int len  = lengths[b];

    // ---- build x features for this token tile ----
    {
        const int t = tid & 31, g = tid >> 5;   // 32 tokens x 8 feature-groups of 4
        const int gt = g0 + t;
        float* xr = &Xs[t][0];
        if (gt == 0) {
#pragma unroll
            for (int q = 0; q < 4; q++) xr[g*4+q] = demo_enc[b*32 + g*4 + q];
        } else if (gt <= TT) {
            const int ti = b*TT + (gt - 1);
            if (g < 4) {
                float tm = times[ti];
#pragma unroll
                for (int q = 0; q < 4; q++) {
                    int f = g*4 + q;
                    xr[f] = (f < 8) ? sinf(tm * INV_TS[f]) : cosf(tm * INV_TS[f-8]);
                }
            } else {
                int m = meas[ti];
                float val = values[ti];
#pragma unroll
                for (int q = 0; q < 4; q++) {
                    int f = g*4 + q;
                    xr[f] = (f == 16) ? val : ((m == f-17) ? 1.f : 0.f);
                }
            }
        } else {
#pragma unroll
            for (int q = 0; q < 4; q++) xr[g*4+q] = 0.f;
        }
    }
    __syncthreads();

    // ---- attention logits s = x . w_eff ; weight = exp(s) (softmax shift cancels) ----
    if (tid < 128) {
        const int t = tid & 31, h = tid >> 5;
        const int gt = g0 + t;
        float s = 0.f;
#pragma unroll
        for (int k = 0; k < 32; k++) s += Xs[t][k] * w_eff[k*4 + h];
        wexp[t][h] = (gt <= len) ? expf(s) : 0.f;   // mask: position <= length valid
    }
    // no barrier needed: wexp consumed only after later __syncthreads()

    const int tj = tid & 15;            // cols tj*8 .. tj*8+7
    const int tk = tid >> 4;            // tokens tk*2, tk*2+1
    const int t0 = tk * 2;

    float acc[2][8];

    // layer 1: X[32] -> H1[128]
    gemm_k32(w1 + tj*8, &Xs[t0][0], &Xs[t0+1][0], acc);
    bias_relu_store(&Hbuf[0][0][0], acc, b1, tj, t0);
    __syncthreads();
    // layer 2: H1 -> H2
    gemm_k128(w2 + tj*8, &Hbuf[0][t0][0], &Hbuf[0][t0+1][0], acc);
    bias_relu_store(&Hbuf[1][0][0], acc, b2, tj, t0);
    __syncthreads();
    // layer 3: H2 -> enc (kept in registers)
    gemm_k128(w3 + tj*8, &Hbuf[1][t0][0], &Hbuf[1][t0+1][0], acc);
    {
        float4 u = *(const float4*)(b3 + tj*8);
        float4 v = *(const float4*)(b3 + tj*8 + 4);
#pragma unroll
        for (int i = 0; i < 2; i++) {
            acc[i][0] = fmaxf(acc[i][0]+u.x, 0.f); acc[i][1] = fmaxf(acc[i][1]+u.y, 0.f);
            acc[i][2] = fmaxf(acc[i][2]+u.z, 0.f); acc[i][3] = fmaxf(acc[i][3]+u.w, 0.f);
            acc[i][4] = fmaxf(acc[i][4]+v.x, 0.f); acc[i][5] = fmaxf(acc[i][5]+v.y, 0.f);
            acc[i][6] = fmaxf(acc[i][6]+v.z, 0.f); acc[i][7] = fmaxf(acc[i][7]+v.w, 0.f);
        }
    }

    // ---- per-thread exp-weighted contributions: c[h][j] = sum_i w(t_i,h)*enc_i[j] ----
    float c[4][8];
#pragma unroll
    for (int h = 0; h < 4; h++)
#pragma unroll
        for (int j = 0; j < 8; j++) c[h][j] = 0.f;
#pragma unroll
    for (int i = 0; i < 2; i++) {
        const int t = t0 + i;
        float w0 = wexp[t][0], w1_ = wexp[t][1], w2_ = wexp[t][2], w3_ = wexp[t][3];
#pragma unroll
        for (int j = 0; j < 8; j++) {
            float e = acc[i][j];
            c[0][j] += w0*e; c[1][j] += w1_*e; c[2][j] += w2_*e; c[3][j] += w3_*e;
        }
    }
    __syncthreads();                    // everyone done reading Hbuf
    // stage contributions into (reused) Hbuf: red[tk][h][j], 16*4*128 floats
    float* red = &Hbuf[0][0][0];
#pragma unroll
    for (int h = 0; h < 4; h++)
#pragma unroll
        for (int j = 0; j < 8; j++)
            red[(tk*4 + h)*128 + tj*8 + j] = c[h][j];
    __syncthreads();
    // reduce 16 token-groups -> tile partial
    float* outp = partials + ((size_t)b*NTILE + tile) * PREC;
#pragma unroll
    for (int r = 0; r < 2; r++) {
        int o = tid + r*256;            // o = h*128 + j
        float s = 0.f;
#pragma unroll
        for (int q = 0; q < 16; q++) s += red[(q*4 + (o>>7))*128 + (o & 127)];
        outp[o] = s;
    }
    if (tid < 4) {
        float z = 0.f;
        for (int t = 0; t < TILE; t++) z += wexp[t][tid];
        outp[512 + tid] = z;
    }
}

// ---------------- final: reduce tiles -> feat -> rho MLP -> sigmoid --------------
__global__ __launch_bounds__(128) void final_kernel(
    const float* __restrict__ partials,
    const float* __restrict__ rw1, const float* __restrict__ rb1,
    const float* __restrict__ rw2, const float* __restrict__ rb2,
    const float* __restrict__ rw3, const float* __restrict__ rb3,
    float* __restrict__ out)
{
    const int b = blockIdx.x, tid = threadIdx.x;
    __shared__ float feat[512];
    __shared__ float r1s[128];
    __shared__ float r2s[128];
    __shared__ float zsh[4];
    const float* pb = partials + (size_t)b * NTILE * PREC;
    if (tid < 4) {
        float z = 0.f;
        for (int t = 0; t < NTILE; t++) z += pb[(size_t)t*PREC + 512 + tid];
        zsh[tid] = z;
    }
    __syncthreads();
#pragma unroll
    for (int r = 0; r < 4; r++) {
        int o = tid + r*128;
        float s = 0.f;
        for (int t = 0; t < NTILE; t++) s += pb[(size_t)t*PREC + o];
        feat[o] = s / zsh[o >> 7];
    }
    __syncthreads();
    float a = rb1[tid];
    for (int k = 0; k < 512; k++) a += feat[k] * rw1[k*128 + tid];
    r1s[tid] = fmaxf(a, 0.f);
    __syncthreads();
    a = rb2[tid];
    for (int k = 0; k < 128; k++) a += r1s[k] * rw2[k*128 + tid];
    r2s[tid] = fmaxf(a, 0.f);
    __syncthreads();
    if (tid == 0) {
        float o = rb3[0];
        for (int k = 0; k < 128; k++) o += r2s[k] * rw3[k];
        out[b] = 1.f / (1.f + expf(-o));
    }
}

extern "C" void kernel_launch(void* const* d_in, const int* in_sizes, int n_in,
                              void* d_out, int out_size, void* d_ws, size_t ws_size,
                              hipStream_t stream) {
    const float* demo    = (const float*)d_in[0];
    const float* times   = (const float*)d_in[1];
    const float* values  = (const float*)d_in[2];
    const int*   meas    = (const int*)  d_in[3];
    const int*   lengths = (const int*)  d_in[4];
    const float* demo_w1 = (const float*)d_in[5];
    const float* demo_b1 = (const float*)d_in[6];
    const float* demo_w2 = (const float*)d_in[7];
    const float* demo_b2 = (const float*)d_in[8];
    const float* phi_w1  = (const float*)d_in[9];
    const float* phi_b1  = (const float*)d_in[10];
    const float* phi_w2  = (const float*)d_in[11];
    const float* phi_b2  = (const float*)d_in[12];
    const float* phi_w3  = (const float*)d_in[13];
    const float* phi_b3  = (const float*)d_in[14];
    // d_in[15..22]: psi network + rho_attn — provably dead code (softmax shift-invariance)
    const float* W_k     = (const float*)d_in[23];
    const float* W_q     = (const float*)d_in[24];
    const float* rho_w1  = (const float*)d_in[25];
    const float* rho_b1  = (const float*)d_in[26];
    const float* rho_w2  = (const float*)d_in[27];
    const float* rho_b2  = (const float*)d_in[28];
    const float* rho_w3  = (const float*)d_in[29];
    const float* rho_b3  = (const float*)d_in[30];

    float* ws       = (float*)d_ws;
    float* demo_enc = ws;                 // 64*32
    float* w_eff    = ws + 2048;          // 32*4
    float* partials = ws + 2176;          // 64*129*516 ≈ 17 MB

    prep_kernel<<<65, 128, 0, stream>>>(demo, demo_w1, demo_b1, demo_w2, demo_b2,
                                        W_k, W_q, demo_enc, w_eff);
    fused_main<<<dim3(NTILE, NB), 256, 0, stream>>>(
        times, values, meas, lengths, demo_enc, w_eff,
        phi_w1, phi_b1, phi_w2, phi_b2, phi_w3, phi_b3, partials);
    final_kernel<<<NB, 128, 0, stream>>>(partials, rho_w1, rho_b1, rho_w2, rho_b2,
                                         rho_w3, rho_b3, (float*)d_out);
}

// Round 2
// 261.320 us; speedup vs baseline: 2.8011x; 2.8011x over previous
//
#include <hip/hip_runtime.h>
#include <math.h>

#define TT     4096     // T
#define MTILE  64       // tokens per workgroup
#define NTILE  65       // ceil((T+1)/MTILE)
#define PREC   516      // per-tile partial record: 4*128 P + 4 z
#define NB     64       // batch

typedef short s16x8 __attribute__((ext_vector_type(8)));
typedef float f32x4 __attribute__((ext_vector_type(4)));

// 100^(-i/7), i=0..7  (inverse timescales)
__device__ __constant__ float INV_TS[8] = {
    1.0f,                 0.5179474679231213f, 0.2682695795279726f, 0.1389495494373138f,
    0.0719685673001152f,  0.0372759372031494f, 0.0193069772888325f, 0.01f };

__device__ __forceinline__ ushort f2bf(float f) {
    uint u = __float_as_uint(f);
    return (ushort)((u + 0x7fffu + ((u >> 16) & 1u)) >> 16);   // RNE
}
__device__ __forceinline__ float bf2f(ushort h) {
    return __uint_as_float(((uint)h) << 16);
}
__device__ __forceinline__ uint pk(ushort a, ushort b) { return (uint)a | ((uint)b << 16); }

// ---------------- prep: demo encoder (blocks 0..63) + w_eff (block 64) ----------
__global__ __launch_bounds__(128) void prep_kernel(
    const float* __restrict__ demo,
    const float* __restrict__ dw1, const float* __restrict__ db1,
    const float* __restrict__ dw2, const float* __restrict__ db2,
    const float* __restrict__ W_k, const float* __restrict__ W_q,
    float* __restrict__ demo_enc, float* __restrict__ w_eff)
{
    const int b = blockIdx.x, tid = threadIdx.x;
    if (b < NB) {
        __shared__ float h[128];
        float a = db1[tid];
#pragma unroll
        for (int k = 0; k < 8; k++) a += demo[b*8 + k] * dw1[k*128 + tid];
        h[tid] = fmaxf(a, 0.f);
        __syncthreads();
        if (tid < 32) {
            float e = db2[tid];
            for (int k = 0; k < 128; k++) e += h[k] * dw2[k*32 + tid];
            demo_enc[b*32 + tid] = e;
        }
    } else {
        // w_eff[f][h] = (W_k[f, h*64:(h+1)*64] . W_q[h]) / 8,  f<32, h<4
        const int f = tid >> 2, hh = tid & 3;
        float s = 0.f;
        for (int d = 0; d < 64; d++) s += W_k[f*256 + hh*64 + d] * W_q[hh*64 + d];
        w_eff[f*4 + hh] = s * 0.125f;
    }
}

// ---------------- prep: transpose + hi/lo-split phi weights into bf16 ----------
// ws16 layout: w1T_hi[128*32] w1T_lo[128*32] w2T_hi[128*128] w2T_lo w3T_hi w3T_lo
__global__ __launch_bounds__(128) void prep_wT(
    const float* __restrict__ w1, const float* __restrict__ w2,
    const float* __restrict__ w3, ushort* __restrict__ ws16)
{
    ushort* w1T_hi = ws16;
    ushort* w1T_lo = ws16 + 4096;
    ushort* w2T_hi = ws16 + 8192;
    ushort* w2T_lo = w2T_hi + 16384;
    ushort* w3T_hi = w2T_lo + 16384;
    ushort* w3T_lo = w3T_hi + 16384;
    const int n = blockIdx.x & 127, which = blockIdx.x >> 7, k = threadIdx.x;
    if (which == 0) {
        float v = w2[k*128 + n]; ushort h = f2bf(v);
        w2T_hi[n*128 + k] = h; w2T_lo[n*128 + k] = f2bf(v - bf2f(h));
    } else if (which == 1) {
        float v = w3[k*128 + n]; ushort h = f2bf(v);
        w3T_hi[n*128 + k] = h; w3T_lo[n*128 + k] = f2bf(v - bf2f(h));
    } else if (k < 32) {
        float v = w1[k*128 + n]; ushort h = f2bf(v);
        w1T_hi[n*32 + k] = h; w1T_lo[n*32 + k] = f2bf(v - bf2f(h));
    }
}

// ---------------- fused main: features -> MFMA phi MLP -> weighted partials -----
__global__ __launch_bounds__(256, 2) void fused_main(
    const float* __restrict__ times,  const float* __restrict__ values,
    const int*   __restrict__ meas,   const int*   __restrict__ lengths,
    const float* __restrict__ demo_enc, const float* __restrict__ w_eff,
    const ushort* __restrict__ wT16,
    const float* __restrict__ b1, const float* __restrict__ b2,
    const float* __restrict__ b3,
    float* __restrict__ partials)
{
    const ushort* w1T_hi = wT16;
    const ushort* w1T_lo = wT16 + 4096;
    const ushort* w2T_hi = wT16 + 8192;
    const ushort* w2T_lo = w2T_hi + 16384;
    const ushort* w3T_hi = w2T_lo + 16384;
    const ushort* w3T_lo = w3T_hi + 16384;

    __shared__ ushort Xhi[64][40],  Xlo[64][40];    // [token][k], k-contig, pad->40
    __shared__ ushort Hhi[64][136], Hlo[64][136];   // [token][k], pad->136
    __shared__ float  wexp[64][4];
    __shared__ float  spart[4][64][4];

    const int tid  = threadIdx.x;
    const int b    = blockIdx.y;
    const int tile = blockIdx.x;
    const int g0   = tile * MTILE;
    const int len  = lengths[b];
    const int t    = tid & 63, g = tid >> 6;
    const int gt   = g0 + t;

    // ---- feature build: thread (t,g) computes features g*8..g*8+7 of token t ----
    float x[8];
    if (gt == 0) {
#pragma unroll
        for (int j = 0; j < 8; j++) x[j] = demo_enc[b*32 + g*8 + j];
    } else if (gt <= TT) {
        const int ti = b*TT + gt - 1;
        if (g == 0) {
            float tm = times[ti];
#pragma unroll
            for (int j = 0; j < 8; j++) x[j] = sinf(tm * INV_TS[j]);
        } else if (g == 1) {
            float tm = times[ti];
#pragma unroll
            for (int j = 0; j < 8; j++) x[j] = cosf(tm * INV_TS[j]);
        } else if (g == 2) {
            int mm = meas[ti]; x[0] = values[ti];
#pragma unroll
            for (int j = 1; j < 8; j++) x[j] = (mm == j-1) ? 1.f : 0.f;
        } else {
            int mm = meas[ti];
#pragma unroll
            for (int j = 0; j < 8; j++) x[j] = (mm == 7+j) ? 1.f : 0.f;
        }
    } else {
#pragma unroll
        for (int j = 0; j < 8; j++) x[j] = 0.f;
    }
    // attention-logit partials (fp32, exact)
    {
        float s0 = 0, s1 = 0, s2 = 0, s3 = 0;
#pragma unroll
        for (int j = 0; j < 8; j++) {
            const float* we = w_eff + (g*8 + j)*4;
            s0 += x[j]*we[0]; s1 += x[j]*we[1]; s2 += x[j]*we[2]; s3 += x[j]*we[3];
        }
        f32x4 sv = {s0, s1, s2, s3};
        *(f32x4*)&spart[g][t][0] = sv;
    }
    // split X into hi/lo bf16
    {
        ushort h[8], l[8];
#pragma unroll
        for (int j = 0; j < 8; j++) { h[j] = f2bf(x[j]); l[j] = f2bf(x[j] - bf2f(h[j])); }
        uint4 uh = {pk(h[0],h[1]), pk(h[2],h[3]), pk(h[4],h[5]), pk(h[6],h[7])};
        uint4 ul = {pk(l[0],l[1]), pk(l[2],l[3]), pk(l[4],l[5]), pk(l[6],l[7])};
        *(uint4*)&Xhi[t][g*8] = uh;
        *(uint4*)&Xlo[t][g*8] = ul;
    }
    __syncthreads();
    // wexp[t][h] — softmax shift cancels; exp never overflows (|s| < ~1)
    {
        float ss = spart[0][t][g] + spart[1][t][g] + spart[2][t][g] + spart[3][t][g];
        wexp[t][g] = (gt <= len) ? expf(ss) : 0.f;
    }

    const int lane = tid & 63, w = tid >> 6;
    const int l15 = lane & 15, q = lane >> 4;
    const int nb0 = w * 32;                        // this wave's 32 output features

    // ================= layer 1: X[64x32] -> H[64x128]  (D' = w1T . X^T) ========
    {
        s16x8 ah[2], al[2]; f32x4 bv[2];
#pragma unroll
        for (int nt = 0; nt < 2; nt++) {
            const int np = nb0 + nt*16 + l15;
            ah[nt] = *(const s16x8*)(w1T_hi + np*32 + q*8);
            al[nt] = *(const s16x8*)(w1T_lo + np*32 + q*8);
            bv[nt] = *(const f32x4*)(b1 + nb0 + nt*16 + q*4);
        }
#pragma unroll
        for (int tt = 0; tt < 4; tt++) {
            const int m = tt*16 + l15;
            s16x8 bh = *(const s16x8*)&Xhi[m][q*8];
            s16x8 bl = *(const s16x8*)&Xlo[m][q*8];
#pragma unroll
            for (int nt = 0; nt < 2; nt++) {
                f32x4 acc = {0.f, 0.f, 0.f, 0.f};
                acc = __builtin_amdgcn_mfma_f32_16x16x32_bf16(al[nt], bh, acc, 0, 0, 0);
                acc = __builtin_amdgcn_mfma_f32_16x16x32_bf16(ah[nt], bl, acc, 0, 0, 0);
                acc = __builtin_amdgcn_mfma_f32_16x16x32_bf16(ah[nt], bh, acc, 0, 0, 0);
                float e0 = fmaxf(acc[0] + bv[nt][0], 0.f);
                float e1 = fmaxf(acc[1] + bv[nt][1], 0.f);
                float e2 = fmaxf(acc[2] + bv[nt][2], 0.f);
                float e3 = fmaxf(acc[3] + bv[nt][3], 0.f);
                ushort h0 = f2bf(e0), h1 = f2bf(e1), h2 = f2bf(e2), h3 = f2bf(e3);
                ushort l0 = f2bf(e0 - bf2f(h0)), l1 = f2bf(e1 - bf2f(h1));
                ushort l2 = f2bf(e2 - bf2f(h2)), l3 = f2bf(e3 - bf2f(h3));
                const int col = nb0 + nt*16 + q*4;     // D rows = output features
                uint2 uh = {pk(h0,h1), pk(h2,h3)};
                uint2 ul = {pk(l0,l1), pk(l2,l3)};
                *(uint2*)&Hhi[m][col] = uh;
                *(uint2*)&Hlo[m][col] = ul;
            }
        }
    }
    __syncthreads();

    // ================= layers 2,3: H -> H (in-place per token-subtile) ==========
#pragma unroll 1
    for (int L = 0; L < 2; L++) {
        const ushort* WH = L ? w3T_hi : w2T_hi;
        const ushort* WL = L ? w3T_lo : w2T_lo;
        const float*  bb = L ? b3 : b2;
        s16x8 ah[2][4], al[2][4]; f32x4 bv[2];
#pragma unroll
        for (int nt = 0; nt < 2; nt++) {
            const int np = nb0 + nt*16 + l15;
#pragma unroll
            for (int ks = 0; ks < 4; ks++) {
                ah[nt][ks] = *(const s16x8*)(WH + np*128 + ks*32 + q*8);
                al[nt][ks] = *(const s16x8*)(WL + np*128 + ks*32 + q*8);
            }
            bv[nt] = *(const f32x4*)(bb + nb0 + nt*16 + q*4);
        }
#pragma unroll
        for (int tt = 0; tt < 4; tt++) {
            const int m = tt*16 + l15;
            s16x8 bh[4], bl[4];
#pragma unroll
            for (int ks = 0; ks < 4; ks++) {
                bh[ks] = *(const s16x8*)&Hhi[m][ks*32 + q*8];
                bl[ks] = *(const s16x8*)&Hlo[m][ks*32 + q*8];
            }
            __syncthreads();   // all waves' reads of subtile tt done -> safe to overwrite
#pragma unroll
            for (int nt = 0; nt < 2; nt++) {
                f32x4 acc = {0.f, 0.f, 0.f, 0.f};
#pragma unroll
                for (int ks = 0; ks < 4; ks++) {
                    acc = __builtin_amdgcn_mfma_f32_16x16x32_bf16(al[nt][ks], bh[ks], acc, 0, 0, 0);
                    acc = __builtin_amdgcn_mfma_f32_16x16x32_bf16(ah[nt][ks], bl[ks], acc, 0, 0, 0);
                    acc = __builtin_amdgcn_mfma_f32_16x16x32_bf16(ah[nt][ks], bh[ks], acc, 0, 0, 0);
                }
                float e0 = fmaxf(acc[0] + bv[nt][0], 0.f);
                float e1 = fmaxf(acc[1] + bv[nt][1], 0.f);
                float e2 = fmaxf(acc[2] + bv[nt][2], 0.f);
                float e3 = fmaxf(acc[3] + bv[nt][3], 0.f);
                ushort h0 = f2bf(e0), h1 = f2bf(e1), h2 = f2bf(e2), h3 = f2bf(e3);
                ushort l0 = f2bf(e0 - bf2f(h0)), l1 = f2bf(e1 - bf2f(h1));
                ushort l2 = f2bf(e2 - bf2f(h2)), l3 = f2bf(e3 - bf2f(h3));
                const int col = nb0 + nt*16 + q*4;
                uint2 uh = {pk(h0,h1), pk(h2,h3)};
                uint2 ul = {pk(l0,l1), pk(l2,l3)};
                *(uint2*)&Hhi[m][col] = uh;
                *(uint2*)&Hlo[m][col] = ul;
            }
        }
        __syncthreads();   // layer complete
    }

    // ================= weighted head partials ==================================
    // wave w = head w; lane covers enc columns 2*lane, 2*lane+1
    {
        float p0 = 0.f, p1 = 0.f, z = 0.f;
        const int c = 2 * lane;
#pragma unroll 4
        for (int t2 = 0; t2 < 64; t2++) {
            uint hh = *(const uint*)&Hhi[t2][c];
            uint ll = *(const uint*)&Hlo[t2][c];
            float e0 = bf2f((ushort)(hh & 0xffffu)) + bf2f((ushort)(ll & 0xffffu));
            float e1 = bf2f((ushort)(hh >> 16))     + bf2f((ushort)(ll >> 16));
            float wx = wexp[t2][w];
            p0 += wx * e0; p1 += wx * e1; z += wx;
        }
        float* outp = partials + ((size_t)b * NTILE + tile) * PREC;
        float2 pv; pv.x = p0; pv.y = p1;
        *(float2*)&outp[w*128 + c] = pv;
        if (lane == 0) outp[512 + w] = z;
    }
}

// ---------------- final: reduce tiles -> feat -> rho MLP -> sigmoid --------------
__global__ __launch_bounds__(128) void final_kernel(
    const float* __restrict__ partials,
    const float* __restrict__ rw1, const float* __restrict__ rb1,
    const float* __restrict__ rw2, const float* __restrict__ rb2,
    const float* __restrict__ rw3, const float* __restrict__ rb3,
    float* __restrict__ out)
{
    const int b = blockIdx.x, tid = threadIdx.x;
    __shared__ float feat[512];
    __shared__ float r1s[128];
    __shared__ float r2s[128];
    __shared__ float zsh[4];
    const float* pb = partials + (size_t)b * NTILE * PREC;
    if (tid < 4) {
        float z = 0.f;
        for (int t = 0; t < NTILE; t++) z += pb[(size_t)t*PREC + 512 + tid];
        zsh[tid] = z;
    }
    __syncthreads();
#pragma unroll
    for (int r = 0; r < 4; r++) {
        int o = tid + r*128;
        float s = 0.f;
        for (int t = 0; t < NTILE; t++) s += pb[(size_t)t*PREC + o];
        feat[o] = s / zsh[o >> 7];
    }
    __syncthreads();
    float a = rb1[tid];
    for (int k = 0; k < 512; k++) a += feat[k] * rw1[k*128 + tid];
    r1s[tid] = fmaxf(a, 0.f);
    __syncthreads();
    a = rb2[tid];
    for (int k = 0; k < 128; k++) a += r1s[k] * rw2[k*128 + tid];
    r2s[tid] = fmaxf(a, 0.f);
    __syncthreads();
    if (tid == 0) {
        float o = rb3[0];
        for (int k = 0; k < 128; k++) o += r2s[k] * rw3[k];
        out[b] = 1.f / (1.f + expf(-o));
    }
}

extern "C" void kernel_launch(void* const* d_in, const int* in_sizes, int n_in,
                              void* d_out, int out_size, void* d_ws, size_t ws_size,
                              hipStream_t stream) {
    const float* demo    = (const float*)d_in[0];
    const float* times   = (const float*)d_in[1];
    const float* values  = (const float*)d_in[2];
    const int*   meas    = (const int*)  d_in[3];
    const int*   lengths = (const int*)  d_in[4];
    const float* demo_w1 = (const float*)d_in[5];
    const float* demo_b1 = (const float*)d_in[6];
    const float* demo_w2 = (const float*)d_in[7];
    const float* demo_b2 = (const float*)d_in[8];
    const float* phi_w1  = (const float*)d_in[9];
    const float* phi_b1  = (const float*)d_in[10];
    const float* phi_w2  = (const float*)d_in[11];
    const float* phi_b2  = (const float*)d_in[12];
    const float* phi_w3  = (const float*)d_in[13];
    const float* phi_b3  = (const float*)d_in[14];
    // d_in[15..22]: psi network + rho_attn — dead code (softmax shift-invariance)
    const float* W_k     = (const float*)d_in[23];
    const float* W_q     = (const float*)d_in[24];
    const float* rho_w1  = (const float*)d_in[25];
    const float* rho_b1  = (const float*)d_in[26];
    const float* rho_w2  = (const float*)d_in[27];
    const float* rho_b2  = (const float*)d_in[28];
    const float* rho_w3  = (const float*)d_in[29];
    const float* rho_b3  = (const float*)d_in[30];

    float*  ws       = (float*)d_ws;
    float*  demo_enc = ws;                    // 64*32 = 2048 floats
    float*  w_eff    = ws + 2048;             // 128 floats
    ushort* wT16     = (ushort*)(ws + 2176);  // 73728 shorts = 36864 floats
    float*  partials = ws + 39040;            // 64*65*516 floats ≈ 8.6 MB

    prep_kernel<<<65, 128, 0, stream>>>(demo, demo_w1, demo_b1, demo_w2, demo_b2,
                                        W_k, W_q, demo_enc, w_eff);
    prep_wT<<<384, 128, 0, stream>>>(phi_w1, phi_w2, phi_w3, wT16);
    fused_main<<<dim3(NTILE, NB), 256, 0, stream>>>(
        times, values, meas, lengths, demo_enc, w_eff, wT16,
        phi_b1, phi_b2, phi_b3, partials);
    final_kernel<<<NB, 128, 0, stream>>>(partials, rho_w1, rho_b1, rho_w2, rho_b2,
                                         rho_w3, rho_b3, (float*)d_out);
}

// Round 3
// 213.912 us; speedup vs baseline: 3.4219x; 1.2216x over previous
//
#include <hip/hip_runtime.h>
#include <math.h>

#define TT     4096     // T
#define MTILE  64       // tokens per workgroup
#define NTILE  65       // ceil((T+1)/MTILE)
#define PREC   516      // per-tile partial record: 4*128 P + 4 z
#define NB     64       // batch

typedef short s16x8 __attribute__((ext_vector_type(8)));
typedef float f32x4 __attribute__((ext_vector_type(4)));

// 100^(-i/7), i=0..7  (inverse timescales)
__device__ __constant__ float INV_TS[8] = {
    1.0f,                 0.5179474679231213f, 0.2682695795279726f, 0.1389495494373138f,
    0.0719685673001152f,  0.0372759372031494f, 0.0193069772888325f, 0.01f };

__device__ __forceinline__ ushort f2bf(float f) {
    uint u = __float_as_uint(f);
    return (ushort)((u + 0x7fffu + ((u >> 16) & 1u)) >> 16);   // RNE
}
__device__ __forceinline__ float bf2f(ushort h) {
    return __uint_as_float(((uint)h) << 16);
}
__device__ __forceinline__ uint pk(ushort a, ushort b) { return (uint)a | ((uint)b << 16); }

// ---------------- prep (merged): demo enc | w_eff | weight transpose+split ------
// blocks 0..63: demo encoder; block 64: w_eff; blocks 65..448: weight prep
__global__ __launch_bounds__(128) void prep_all(
    const float* __restrict__ demo,
    const float* __restrict__ dw1, const float* __restrict__ db1,
    const float* __restrict__ dw2, const float* __restrict__ db2,
    const float* __restrict__ W_k, const float* __restrict__ W_q,
    const float* __restrict__ w1, const float* __restrict__ w2,
    const float* __restrict__ w3,
    float* __restrict__ demo_enc, float* __restrict__ w_eff,
    ushort* __restrict__ ws16)
{
    const int b = blockIdx.x, tid = threadIdx.x;
    if (b < NB) {
        __shared__ float h[128];
        float a = db1[tid];
#pragma unroll
        for (int k = 0; k < 8; k++) a += demo[b*8 + k] * dw1[k*128 + tid];
        h[tid] = fmaxf(a, 0.f);
        __syncthreads();
        if (tid < 32) {
            float e = db2[tid];
            for (int k = 0; k < 128; k++) e += h[k] * dw2[k*32 + tid];
            demo_enc[b*32 + tid] = e;
        }
    } else if (b == NB) {
        // w_eff[f][h] = (W_k[f, h*64:(h+1)*64] . W_q[h]) / 8,  f<32, h<4
        const int f = tid >> 2, hh = tid & 3;
        float s = 0.f;
        for (int d = 0; d < 64; d++) s += W_k[f*256 + hh*64 + d] * W_q[hh*64 + d];
        w_eff[f*4 + hh] = s * 0.125f;
    } else {
        ushort* w1T_hi = ws16;
        ushort* w1T_lo = ws16 + 4096;
        ushort* w2T_hi = ws16 + 8192;
        ushort* w2T_lo = w2T_hi + 16384;
        ushort* w3T_hi = w2T_lo + 16384;
        const int n = (b - 65) & 127, which = (b - 65) >> 7, k = tid;
        if (which == 0) {
            float v = w2[k*128 + n]; ushort h = f2bf(v);
            w2T_hi[n*128 + k] = h; w2T_lo[n*128 + k] = f2bf(v - bf2f(h));
        } else if (which == 1) {
            w3T_hi[n*128 + k] = f2bf(w3[k*128 + n]);       // L3: single-term
        } else if (k < 32) {
            float v = w1[k*128 + n]; ushort h = f2bf(v);
            w1T_hi[n*32 + k] = h; w1T_lo[n*32 + k] = f2bf(v - bf2f(h));
        }
    }
}

// ---------------- fused main: features -> MFMA phi MLP -> weighted partials -----
__global__ __launch_bounds__(256, 4) void fused_main(
    const float* __restrict__ times,  const float* __restrict__ values,
    const int*   __restrict__ meas,   const int*   __restrict__ lengths,
    const float* __restrict__ demo_enc, const float* __restrict__ w_eff,
    const ushort* __restrict__ wT16,
    const float* __restrict__ b1, const float* __restrict__ b2,
    const float* __restrict__ b3,
    float* __restrict__ partials)
{
    const ushort* w1T_hi = wT16;
    const ushort* w1T_lo = wT16 + 4096;
    const ushort* w2T_hi = wT16 + 8192;
    const ushort* w2T_lo = w2T_hi + 16384;
    const ushort* w3T_hi = w2T_lo + 16384;

    __shared__ ushort Xhi[64][40];          // [token][k], hi only, pad->40
    __shared__ ushort Hhi[64][136];         // [token][k], hi only, pad->136
    __shared__ float  wexp[64][4];          // f32x4 per token
    __shared__ float  spart[4][64][4];

    const int tid  = threadIdx.x;
    const int b    = blockIdx.y;
    const int tile = blockIdx.x;
    const int g0   = tile * MTILE;
    const int len  = lengths[b];
    const int t    = tid & 63, g = tid >> 6;
    const int gt   = g0 + t;

    // ---- feature build: thread (t,g) computes features g*8..g*8+7 of token t ----
    float x[8];
    if (gt == 0) {
#pragma unroll
        for (int j = 0; j < 8; j++) x[j] = demo_enc[b*32 + g*8 + j];
    } else if (gt <= TT) {
        const int ti = b*TT + gt - 1;
        if (g == 0) {
            float tm = times[ti];
#pragma unroll
            for (int j = 0; j < 8; j++) x[j] = sinf(tm * INV_TS[j]);
        } else if (g == 1) {
            float tm = times[ti];
#pragma unroll
            for (int j = 0; j < 8; j++) x[j] = cosf(tm * INV_TS[j]);
        } else if (g == 2) {
            int mm = meas[ti]; x[0] = values[ti];
#pragma unroll
            for (int j = 1; j < 8; j++) x[j] = (mm == j-1) ? 1.f : 0.f;
        } else {
            int mm = meas[ti];
#pragma unroll
            for (int j = 0; j < 8; j++) x[j] = (mm == 7+j) ? 1.f : 0.f;
        }
    } else {
#pragma unroll
        for (int j = 0; j < 8; j++) x[j] = 0.f;
    }
    // attention-logit partials (fp32, exact features)
    {
        float s0 = 0, s1 = 0, s2 = 0, s3 = 0;
#pragma unroll
        for (int j = 0; j < 8; j++) {
            const float* we = w_eff + (g*8 + j)*4;
            s0 += x[j]*we[0]; s1 += x[j]*we[1]; s2 += x[j]*we[2]; s3 += x[j]*we[3];
        }
        f32x4 sv = {s0, s1, s2, s3};
        *(f32x4*)&spart[g][t][0] = sv;
    }
    // X -> bf16 (hi only)
    {
        ushort h[8];
#pragma unroll
        for (int j = 0; j < 8; j++) h[j] = f2bf(x[j]);
        uint4 uh = {pk(h[0],h[1]), pk(h[2],h[3]), pk(h[4],h[5]), pk(h[6],h[7])};
        *(uint4*)&Xhi[t][g*8] = uh;
    }
    __syncthreads();
    // wexp[t][h] — softmax shift cancels; exp never overflows (|s| small)
    {
        float ss = spart[0][t][g] + spart[1][t][g] + spart[2][t][g] + spart[3][t][g];
        wexp[t][g] = (gt <= len) ? expf(ss) : 0.f;
    }

    const int lane = tid & 63, wav = tid >> 6;
    const int l15 = lane & 15, q = lane >> 4;
    const int nb0 = wav * 32;                      // this wave's 32 features

    // ====== layer 1: A=weights (2-term), B=X (hi) -> Hhi; D col=token,row=feat ==
    {
        s16x8 ah[2], al[2]; f32x4 bv[2];
#pragma unroll
        for (int nt = 0; nt < 2; nt++) {
            const int np = nb0 + nt*16 + l15;
            ah[nt] = *(const s16x8*)(w1T_hi + np*32 + q*8);
            al[nt] = *(const s16x8*)(w1T_lo + np*32 + q*8);
            bv[nt] = *(const f32x4*)(b1 + nb0 + nt*16 + q*4);
        }
#pragma unroll
        for (int tt = 0; tt < 4; tt++) {
            const int m = tt*16 + l15;
            s16x8 bh = *(const s16x8*)&Xhi[m][q*8];
#pragma unroll
            for (int nt = 0; nt < 2; nt++) {
                f32x4 acc = {0.f, 0.f, 0.f, 0.f};
                acc = __builtin_amdgcn_mfma_f32_16x16x32_bf16(al[nt], bh, acc, 0, 0, 0);
                acc = __builtin_amdgcn_mfma_f32_16x16x32_bf16(ah[nt], bh, acc, 0, 0, 0);
                ushort h0 = f2bf(fmaxf(acc[0] + bv[nt][0], 0.f));
                ushort h1 = f2bf(fmaxf(acc[1] + bv[nt][1], 0.f));
                ushort h2 = f2bf(fmaxf(acc[2] + bv[nt][2], 0.f));
                ushort h3 = f2bf(fmaxf(acc[3] + bv[nt][3], 0.f));
                uint2 uh = {pk(h0,h1), pk(h2,h3)};
                *(uint2*)&Hhi[m][nb0 + nt*16 + q*4] = uh;
            }
        }
    }
    __syncthreads();

    // ====== layer 2: in-place, weights 2-term, activations hi ===================
    {
        s16x8 ah[2][4], al[2][4]; f32x4 bv[2];
#pragma unroll
        for (int nt = 0; nt < 2; nt++) {
            const int np = nb0 + nt*16 + l15;
#pragma unroll
            for (int ks = 0; ks < 4; ks++) {
                ah[nt][ks] = *(const s16x8*)(w2T_hi + np*128 + ks*32 + q*8);
                al[nt][ks] = *(const s16x8*)(w2T_lo + np*128 + ks*32 + q*8);
            }
            bv[nt] = *(const f32x4*)(b2 + nb0 + nt*16 + q*4);
        }
#pragma unroll
        for (int tt = 0; tt < 4; tt++) {
            const int m = tt*16 + l15;
            s16x8 bh[4];
#pragma unroll
            for (int ks = 0; ks < 4; ks++) bh[ks] = *(const s16x8*)&Hhi[m][ks*32 + q*8];
            __syncthreads();   // all waves done reading token-subtile tt
#pragma unroll
            for (int nt = 0; nt < 2; nt++) {
                f32x4 acc = {0.f, 0.f, 0.f, 0.f};
#pragma unroll
                for (int ks = 0; ks < 4; ks++) {
                    acc = __builtin_amdgcn_mfma_f32_16x16x32_bf16(al[nt][ks], bh[ks], acc, 0, 0, 0);
                    acc = __builtin_amdgcn_mfma_f32_16x16x32_bf16(ah[nt][ks], bh[ks], acc, 0, 0, 0);
                }
                ushort h0 = f2bf(fmaxf(acc[0] + bv[nt][0], 0.f));
                ushort h1 = f2bf(fmaxf(acc[1] + bv[nt][1], 0.f));
                ushort h2 = f2bf(fmaxf(acc[2] + bv[nt][2], 0.f));
                ushort h3 = f2bf(fmaxf(acc[3] + bv[nt][3], 0.f));
                uint2 uh = {pk(h0,h1), pk(h2,h3)};
                *(uint2*)&Hhi[m][nb0 + nt*16 + q*4] = uh;
            }
        }
    }
    __syncthreads();

    // ====== layer 3 (operands swapped: A=tokens, B=weights, single-term) ========
    // D[row=q*4+reg -> token tt*16+q*4+reg][col=l15 -> feature nb0+nt*16+l15]
    {
        s16x8 wb3[2][4];
        float b3l[2];
#pragma unroll
        for (int nt = 0; nt < 2; nt++) {
            const int np = nb0 + nt*16 + l15;
#pragma unroll
            for (int ks = 0; ks < 4; ks++)
                wb3[nt][ks] = *(const s16x8*)(w3T_hi + np*128 + ks*32 + q*8);
            b3l[nt] = b3[np];
        }
        float p2[2][4] = {{0.f,0.f,0.f,0.f},{0.f,0.f,0.f,0.f}};
        float zz[4] = {0.f,0.f,0.f,0.f};
#pragma unroll
        for (int tt = 0; tt < 4; tt++) {
            const int m = tt*16 + l15;
            s16x8 a3[4];
#pragma unroll
            for (int ks = 0; ks < 4; ks++) a3[ks] = *(const s16x8*)&Hhi[m][ks*32 + q*8];
            f32x4 acc0 = {0.f,0.f,0.f,0.f}, acc1 = {0.f,0.f,0.f,0.f};
#pragma unroll
            for (int ks = 0; ks < 4; ks++) {
                acc0 = __builtin_amdgcn_mfma_f32_16x16x32_bf16(a3[ks], wb3[0][ks], acc0, 0, 0, 0);
                acc1 = __builtin_amdgcn_mfma_f32_16x16x32_bf16(a3[ks], wb3[1][ks], acc1, 0, 0, 0);
            }
#pragma unroll
            for (int r = 0; r < 4; r++) {
                f32x4 w4 = *(const f32x4*)&wexp[tt*16 + q*4 + r][0];
                float e0 = fmaxf(acc0[r] + b3l[0], 0.f);
                float e1 = fmaxf(acc1[r] + b3l[1], 0.f);
#pragma unroll
                for (int h = 0; h < 4; h++) {
                    p2[0][h] += w4[h] * e0;
                    p2[1][h] += w4[h] * e1;
                    zz[h]    += w4[h];
                }
            }
        }
        // butterfly over the 4 quads (lanes xor 16, 32) -> full 64-token sums
#pragma unroll
        for (int mask = 16; mask <= 32; mask <<= 1) {
#pragma unroll
            for (int nt = 0; nt < 2; nt++)
#pragma unroll
                for (int h = 0; h < 4; h++) p2[nt][h] += __shfl_xor(p2[nt][h], mask);
#pragma unroll
            for (int h = 0; h < 4; h++) zz[h] += __shfl_xor(zz[h], mask);
        }
        if (q == 0) {
            float* outp = partials + ((size_t)b * NTILE + tile) * PREC;
#pragma unroll
            for (int nt = 0; nt < 2; nt++)
#pragma unroll
                for (int h = 0; h < 4; h++)
                    outp[h*128 + nb0 + nt*16 + l15] = p2[nt][h];
            if (wav == 0 && l15 == 0) {
                f32x4 zv = {zz[0], zz[1], zz[2], zz[3]};
                *(f32x4*)&outp[512] = zv;
            }
        }
    }
}

// ---------------- final: reduce tiles -> feat -> rho MLP -> sigmoid --------------
__global__ __launch_bounds__(128) void final_kernel(
    const float* __restrict__ partials,
    const float* __restrict__ rw1, const float* __restrict__ rb1,
    const float* __restrict__ rw2, const float* __restrict__ rb2,
    const float* __restrict__ rw3, const float* __restrict__ rb3,
    float* __restrict__ out)
{
    const int b = blockIdx.x, tid = threadIdx.x;
    __shared__ float feat[512];
    __shared__ float r1s[128];
    __shared__ float r2s[128];
    __shared__ float zsh[4];
    const float* pb = partials + (size_t)b * NTILE * PREC;
    if (tid < 4) {
        float z = 0.f;
        for (int t = 0; t < NTILE; t++) z += pb[(size_t)t*PREC + 512 + tid];
        zsh[tid] = z;
    }
    __syncthreads();
#pragma unroll
    for (int r = 0; r < 4; r++) {
        int o = tid + r*128;
        float s = 0.f;
        for (int t = 0; t < NTILE; t++) s += pb[(size_t)t*PREC + o];
        feat[o] = s / zsh[o >> 7];
    }
    __syncthreads();
    float a = rb1[tid];
    for (int k = 0; k < 512; k++) a += feat[k] * rw1[k*128 + tid];
    r1s[tid] = fmaxf(a, 0.f);
    __syncthreads();
    a = rb2[tid];
    for (int k = 0; k < 128; k++) a += r1s[k] * rw2[k*128 + tid];
    r2s[tid] = fmaxf(a, 0.f);
    __syncthreads();
    if (tid == 0) {
        float o = rb3[0];
        for (int k = 0; k < 128; k++) o += r2s[k] * rw3[k];
        out[b] = 1.f / (1.f + expf(-o));
    }
}

extern "C" void kernel_launch(void* const* d_in, const int* in_sizes, int n_in,
                              void* d_out, int out_size, void* d_ws, size_t ws_size,
                              hipStream_t stream) {
    const float* demo    = (const float*)d_in[0];
    const float* times   = (const float*)d_in[1];
    const float* values  = (const float*)d_in[2];
    const int*   meas    = (const int*)  d_in[3];
    const int*   lengths = (const int*)  d_in[4];
    const float* demo_w1 = (const float*)d_in[5];
    const float* demo_b1 = (const float*)d_in[6];
    const float* demo_w2 = (const float*)d_in[7];
    const float* demo_b2 = (const float*)d_in[8];
    const float* phi_w1  = (const float*)d_in[9];
    const float* phi_b1  = (const float*)d_in[10];
    const float* phi_w2  = (const float*)d_in[11];
    const float* phi_b2  = (const float*)d_in[12];
    const float* phi_w3  = (const float*)d_in[13];
    const float* phi_b3  = (const float*)d_in[14];
    // d_in[15..22]: psi network + rho_attn — dead code (softmax shift-invariance)
    const float* W_k     = (const float*)d_in[23];
    const float* W_q     = (const float*)d_in[24];
    const float* rho_w1  = (const float*)d_in[25];
    const float* rho_b1  = (const float*)d_in[26];
    const float* rho_w2  = (const float*)d_in[27];
    const float* rho_b2  = (const float*)d_in[28];
    const float* rho_w3  = (const float*)d_in[29];
    const float* rho_b3  = (const float*)d_in[30];

    float*  ws       = (float*)d_ws;
    float*  demo_enc = ws;                    // 64*32 = 2048 floats
    float*  w_eff    = ws + 2048;             // 128 floats
    ushort* wT16     = (ushort*)(ws + 2176);  // 73728 shorts = 36864 floats
    float*  partials = ws + 39040;            // 64*65*516 floats ≈ 8.6 MB

    prep_all<<<449, 128, 0, stream>>>(demo, demo_w1, demo_b1, demo_w2, demo_b2,
                                      W_k, W_q, phi_w1, phi_w2, phi_w3,
                                      demo_enc, w_eff, wT16);
    fused_main<<<dim3(NTILE, NB), 256, 0, stream>>>(
        times, values, meas, lengths, demo_enc, w_eff, wT16,
        phi_b1, phi_b2, phi_b3, partials);
    final_kernel<<<NB, 128, 0, stream>>>(partials, rho_w1, rho_b1, rho_w2, rho_b2,
                                         rho_w3, rho_b3, (float*)d_out);
}

// Round 4
// 181.633 us; speedup vs baseline: 4.0300x; 1.1777x over previous
//
#include <hip/hip_runtime.h>
#include <math.h>

#define TT     4096     // T
#define NTILE  65       // ceil((T+1)/64)
#define NCHUNK (NTILE*64)  // 4160 (b,tile) chunks
#define NWG    512      // persistent workgroups (2/CU)
#define PREC   516      // per-batch accumulator: 4*128 P + 4 z
#define NB     64       // batch

typedef short s16x8 __attribute__((ext_vector_type(8)));
typedef float f32x4 __attribute__((ext_vector_type(4)));

// 100^(-i/7), i=0..7  (inverse timescales)
__device__ __constant__ float INV_TS[8] = {
    1.0f,                 0.5179474679231213f, 0.2682695795279726f, 0.1389495494373138f,
    0.0719685673001152f,  0.0372759372031494f, 0.0193069772888325f, 0.01f };

__device__ __forceinline__ ushort f2bf(float f) {        // RNE (prep only)
    uint u = __float_as_uint(f);
    return (ushort)((u + 0x7fffu + ((u >> 16) & 1u)) >> 16);
}
__device__ __forceinline__ float bf2f(ushort h) {
    return __uint_as_float(((uint)h) << 16);
}
// fast round-half-up bf16: 0.5-ulp max error, cheap
__device__ __forceinline__ uint pk2r(float a, float b) {
    return ((__float_as_uint(a) + 0x8000u) >> 16) |
           ((__float_as_uint(b) + 0x8000u) & 0xffff0000u);
}

// ---------------- prep: demo enc + zero partials | w_eff | weight prep ----------
__global__ __launch_bounds__(128) void prep_all(
    const float* __restrict__ demo,
    const float* __restrict__ dw1, const float* __restrict__ db1,
    const float* __restrict__ dw2, const float* __restrict__ db2,
    const float* __restrict__ W_k, const float* __restrict__ W_q,
    const float* __restrict__ w1, const float* __restrict__ w2,
    const float* __restrict__ w3,
    float* __restrict__ demo_enc, float* __restrict__ w_eff,
    ushort* __restrict__ ws16, float* __restrict__ partials)
{
    const int b = blockIdx.x, tid = threadIdx.x;
    if (b < NB) {
        // zero this batch's accumulator record (ws is poisoned every call)
        for (int j = tid; j < PREC; j += 128) partials[b*PREC + j] = 0.f;
        __shared__ float h[128];
        float a = db1[tid];
#pragma unroll
        for (int k = 0; k < 8; k++) a += demo[b*8 + k] * dw1[k*128 + tid];
        h[tid] = fmaxf(a, 0.f);
        __syncthreads();
        if (tid < 32) {
            float e = db2[tid];
            for (int k = 0; k < 128; k++) e += h[k] * dw2[k*32 + tid];
            demo_enc[b*32 + tid] = e;
        }
    } else if (b == NB) {
        // w_eff[f][h] = (W_k[f, h*64:(h+1)*64] . W_q[h]) / 8
        const int f = tid >> 2, hh = tid & 3;
        float s = 0.f;
        for (int d = 0; d < 64; d++) s += W_k[f*256 + hh*64 + d] * W_q[hh*64 + d];
        w_eff[f*4 + hh] = s * 0.125f;
    } else {
        ushort* w1T_hi = ws16;
        ushort* w2T_hi = ws16 + 8192;
        ushort* w2T_lo = w2T_hi + 16384;
        ushort* w3T_hi = w2T_lo + 16384;
        const int n = (b - 65) & 127, which = (b - 65) >> 7, k = tid;
        if (which == 0) {
            float v = w2[k*128 + n]; ushort h = f2bf(v);
            w2T_hi[n*128 + k] = h; w2T_lo[n*128 + k] = f2bf(v - bf2f(h));
        } else if (which == 1) {
            w3T_hi[n*128 + k] = f2bf(w3[k*128 + n]);       // L3: single-term
        } else if (k < 32) {
            w1T_hi[n*32 + k] = f2bf(w1[k*128 + n]);        // L1: single-term
        }
    }
}

// ---------------- persistent fused main ----------------------------------------
__global__ __launch_bounds__(256, 2) void fused_main(
    const float* __restrict__ times,  const float* __restrict__ values,
    const int*   __restrict__ meas,   const int*   __restrict__ lengths,
    const float* __restrict__ demo_enc, const float* __restrict__ w_eff,
    const ushort* __restrict__ wT16,
    const float* __restrict__ b1, const float* __restrict__ b2,
    const float* __restrict__ b3,
    float* __restrict__ partials)
{
    const ushort* w1T_hi = wT16;
    const ushort* w2T_hi = wT16 + 8192;
    const ushort* w2T_lo = w2T_hi + 16384;
    const ushort* w3T_hi = w2T_lo + 16384;

    __shared__ ushort Xhi[64][40];          // [token][k] pad->40
    __shared__ ushort Hhi[64][136];         // layer-1 out
    __shared__ ushort H2[64][136];          // layer-2 out (double buffer)
    __shared__ float  wexp[64][4];
    __shared__ float  spart[4][64][4];

    const int tid  = threadIdx.x;
    const int lane = tid & 63, wav = tid >> 6;
    const int l15  = lane & 15, q = lane >> 4;
    const int nb0  = wav * 32;
    const int t    = lane;                  // token slot; wav = feature-group g

    // ---- load this wave's weight fragments ONCE (register-resident) ----
    s16x8 ah1[2];              f32x4 bv1[2];
    s16x8 ah2[2][4], al2[2][4]; f32x4 bv2[2];
    s16x8 wb3[2][4];           float b3l[2];
#pragma unroll
    for (int nt = 0; nt < 2; nt++) {
        const int np = nb0 + nt*16 + l15;
        ah1[nt] = *(const s16x8*)(w1T_hi + np*32 + q*8);
        bv1[nt] = *(const f32x4*)(b1 + nb0 + nt*16 + q*4);
#pragma unroll
        for (int ks = 0; ks < 4; ks++) {
            ah2[nt][ks] = *(const s16x8*)(w2T_hi + np*128 + ks*32 + q*8);
            al2[nt][ks] = *(const s16x8*)(w2T_lo + np*128 + ks*32 + q*8);
            wb3[nt][ks] = *(const s16x8*)(w3T_hi + np*128 + ks*32 + q*8);
        }
        bv2[nt] = *(const f32x4*)(b2 + nb0 + nt*16 + q*4);
        b3l[nt] = b3[np];
    }

    int c = blockIdx.x;
    // ---- prefetch inputs for first chunk ----
    float pf_tm = 0.f, pf_vl = 0.f; int pf_mm = -1;
    {
        const int bb = c / 65, gt = (c % 65) * 64 + t;
        if (gt >= 1 && gt <= TT) {
            const int ti = bb*TT + gt - 1;
            pf_tm = times[ti]; pf_vl = values[ti]; pf_mm = meas[ti];
        }
    }

#pragma unroll 1
    while (c < NCHUNK) {
        const int b = c / 65, tile = c % 65;
        const int gt = tile * 64 + t;
        const int len = lengths[b];

        // ---- feature build (wave w handles feature group w: divergence-free) ----
        float x[8];
        if (gt == 0) {
#pragma unroll
            for (int j = 0; j < 8; j++) x[j] = demo_enc[b*32 + wav*8 + j];
        } else if (gt <= TT) {
            if (wav == 0) {
#pragma unroll
                for (int j = 0; j < 8; j++) x[j] = sinf(pf_tm * INV_TS[j]);
            } else if (wav == 1) {
#pragma unroll
                for (int j = 0; j < 8; j++) x[j] = cosf(pf_tm * INV_TS[j]);
            } else if (wav == 2) {
                x[0] = pf_vl;
#pragma unroll
                for (int j = 1; j < 8; j++) x[j] = (pf_mm == j-1) ? 1.f : 0.f;
            } else {
#pragma unroll
                for (int j = 0; j < 8; j++) x[j] = (pf_mm == 7+j) ? 1.f : 0.f;
            }
        } else {
#pragma unroll
            for (int j = 0; j < 8; j++) x[j] = 0.f;
        }
        // attention-logit partials (fp32 exact features)
        {
            float s0 = 0, s1 = 0, s2 = 0, s3 = 0;
#pragma unroll
            for (int j = 0; j < 8; j++) {
                const float* we = w_eff + (wav*8 + j)*4;
                s0 += x[j]*we[0]; s1 += x[j]*we[1]; s2 += x[j]*we[2]; s3 += x[j]*we[3];
            }
            f32x4 sv = {s0, s1, s2, s3};
            *(f32x4*)&spart[wav][t][0] = sv;
        }
        // X -> bf16 hi
        {
            uint4 uh = {pk2r(x[0],x[1]), pk2r(x[2],x[3]), pk2r(x[4],x[5]), pk2r(x[6],x[7])};
            *(uint4*)&Xhi[t][wav*8] = uh;
        }
        // ---- prefetch next chunk's raw inputs (overlaps all compute below) ----
        const int cn = c + NWG;
        if (cn < NCHUNK) {
            const int bb = cn / 65, gt2 = (cn % 65) * 64 + t;
            if (gt2 >= 1 && gt2 <= TT) {
                const int ti = bb*TT + gt2 - 1;
                pf_tm = times[ti]; pf_vl = values[ti]; pf_mm = meas[ti];
            } else { pf_mm = -1; }
        }
        __syncthreads();                               // B1
        // wexp (softmax shift cancels; |logit| small so exp safe)
        {
            float ss = spart[0][t][wav] + spart[1][t][wav]
                     + spart[2][t][wav] + spart[3][t][wav];
            wexp[t][wav] = (gt <= len) ? __expf(ss) : 0.f;
        }

        // ====== layer 1: A=w1 (regs), B=X -> Hhi ======
#pragma unroll
        for (int tt = 0; tt < 4; tt++) {
            const int m = tt*16 + l15;
            s16x8 bh = *(const s16x8*)&Xhi[m][q*8];
#pragma unroll
            for (int nt = 0; nt < 2; nt++) {
                f32x4 acc = {0.f, 0.f, 0.f, 0.f};
                acc = __builtin_amdgcn_mfma_f32_16x16x32_bf16(ah1[nt], bh, acc, 0, 0, 0);
                uint2 uh = {pk2r(fmaxf(acc[0]+bv1[nt][0],0.f), fmaxf(acc[1]+bv1[nt][1],0.f)),
                            pk2r(fmaxf(acc[2]+bv1[nt][2],0.f), fmaxf(acc[3]+bv1[nt][3],0.f))};
                *(uint2*)&Hhi[m][nb0 + nt*16 + q*4] = uh;
            }
        }
        __syncthreads();                               // B2

        // ====== layer 2: A=w2 (2-term, regs), B=Hhi -> H2 ======
#pragma unroll
        for (int tt = 0; tt < 4; tt++) {
            const int m = tt*16 + l15;
            s16x8 bh[4];
#pragma unroll
            for (int ks = 0; ks < 4; ks++) bh[ks] = *(const s16x8*)&Hhi[m][ks*32 + q*8];
#pragma unroll
            for (int nt = 0; nt < 2; nt++) {
                f32x4 acc = {0.f, 0.f, 0.f, 0.f};
#pragma unroll
                for (int ks = 0; ks < 4; ks++) {
                    acc = __builtin_amdgcn_mfma_f32_16x16x32_bf16(al2[nt][ks], bh[ks], acc, 0, 0, 0);
                    acc = __builtin_amdgcn_mfma_f32_16x16x32_bf16(ah2[nt][ks], bh[ks], acc, 0, 0, 0);
                }
                uint2 uh = {pk2r(fmaxf(acc[0]+bv2[nt][0],0.f), fmaxf(acc[1]+bv2[nt][1],0.f)),
                            pk2r(fmaxf(acc[2]+bv2[nt][2],0.f), fmaxf(acc[3]+bv2[nt][3],0.f))};
                *(uint2*)&H2[m][nb0 + nt*16 + q*4] = uh;
            }
        }
        __syncthreads();                               // B3

        // ====== layer 3: A=tokens (H2), B=w3 (regs); D row=token, col=feature ===
        {
            float p2[2][4] = {{0.f,0.f,0.f,0.f},{0.f,0.f,0.f,0.f}};
            float zz[4]    = {0.f,0.f,0.f,0.f};
#pragma unroll
            for (int tt = 0; tt < 4; tt++) {
                const int m = tt*16 + l15;
                s16x8 a3[4];
#pragma unroll
                for (int ks = 0; ks < 4; ks++) a3[ks] = *(const s16x8*)&H2[m][ks*32 + q*8];
                f32x4 acc0 = {0.f,0.f,0.f,0.f}, acc1 = {0.f,0.f,0.f,0.f};
#pragma unroll
                for (int ks = 0; ks < 4; ks++) {
                    acc0 = __builtin_amdgcn_mfma_f32_16x16x32_bf16(a3[ks], wb3[0][ks], acc0, 0, 0, 0);
                    acc1 = __builtin_amdgcn_mfma_f32_16x16x32_bf16(a3[ks], wb3[1][ks], acc1, 0, 0, 0);
                }
#pragma unroll
                for (int r = 0; r < 4; r++) {
                    f32x4 w4 = *(const f32x4*)&wexp[tt*16 + q*4 + r][0];
                    float e0 = fmaxf(acc0[r] + b3l[0], 0.f);
                    float e1 = fmaxf(acc1[r] + b3l[1], 0.f);
#pragma unroll
                    for (int h = 0; h < 4; h++) {
                        p2[0][h] += w4[h] * e0;
                        p2[1][h] += w4[h] * e1;
                        zz[h]    += w4[h];
                    }
                }
            }
            // butterfly over quads -> full 64-token sums in every lane
#pragma unroll
            for (int mask = 16; mask <= 32; mask <<= 1) {
#pragma unroll
                for (int nt = 0; nt < 2; nt++)
#pragma unroll
                    for (int h = 0; h < 4; h++) p2[nt][h] += __shfl_xor(p2[nt][h], mask);
#pragma unroll
                for (int h = 0; h < 4; h++) zz[h] += __shfl_xor(zz[h], mask);
            }
            // lane q contributes head h=q  (cndmask select, no indexed regs)
            float s0 = (q==0)?p2[0][0]:(q==1)?p2[0][1]:(q==2)?p2[0][2]:p2[0][3];
            float s1 = (q==0)?p2[1][0]:(q==1)?p2[1][1]:(q==2)?p2[1][2]:p2[1][3];
            float* outp = partials + (size_t)b * PREC;
            atomicAdd(&outp[q*128 + nb0 + l15],      s0);
            atomicAdd(&outp[q*128 + nb0 + 16 + l15], s1);
            if (wav == 0 && l15 == 0) {
                float sz = (q==0)?zz[0]:(q==1)?zz[1]:(q==2)?zz[2]:zz[3];
                atomicAdd(&outp[512 + q], sz);
            }
        }
        c = cn;
    }
}

// ---------------- final: feat -> rho MLP -> sigmoid ----------------------------
__global__ __launch_bounds__(128) void final_kernel(
    const float* __restrict__ partials,
    const float* __restrict__ rw1, const float* __restrict__ rb1,
    const float* __restrict__ rw2, const float* __restrict__ rb2,
    const float* __restrict__ rw3, const float* __restrict__ rb3,
    float* __restrict__ out)
{
    const int b = blockIdx.x, tid = threadIdx.x;
    __shared__ float feat[512];
    __shared__ float r1s[128];
    __shared__ float r2s[128];
    __shared__ float zsh[4];
    const float* pb = partials + (size_t)b * PREC;
    if (tid < 4) zsh[tid] = pb[512 + tid];
    __syncthreads();
#pragma unroll
    for (int r = 0; r < 4; r++) {
        int o = tid + r*128;
        feat[o] = pb[o] / zsh[o >> 7];
    }
    __syncthreads();
    float a = rb1[tid];
    for (int k = 0; k < 512; k++) a += feat[k] * rw1[k*128 + tid];
    r1s[tid] = fmaxf(a, 0.f);
    __syncthreads();
    a = rb2[tid];
    for (int k = 0; k < 128; k++) a += r1s[k] * rw2[k*128 + tid];
    r2s[tid] = fmaxf(a, 0.f);
    __syncthreads();
    if (tid == 0) {
        float o = rb3[0];
        for (int k = 0; k < 128; k++) o += r2s[k] * rw3[k];
        out[b] = 1.f / (1.f + expf(-o));
    }
}

extern "C" void kernel_launch(void* const* d_in, const int* in_sizes, int n_in,
                              void* d_out, int out_size, void* d_ws, size_t ws_size,
                              hipStream_t stream) {
    const float* demo    = (const float*)d_in[0];
    const float* times   = (const float*)d_in[1];
    const float* values  = (const float*)d_in[2];
    const int*   meas    = (const int*)  d_in[3];
    const int*   lengths = (const int*)  d_in[4];
    const float* demo_w1 = (const float*)d_in[5];
    const float* demo_b1 = (const float*)d_in[6];
    const float* demo_w2 = (const float*)d_in[7];
    const float* demo_b2 = (const float*)d_in[8];
    const float* phi_w1  = (const float*)d_in[9];
    const float* phi_b1  = (const float*)d_in[10];
    const float* phi_w2  = (const float*)d_in[11];
    const float* phi_b2  = (const float*)d_in[12];
    const float* phi_w3  = (const float*)d_in[13];
    const float* phi_b3  = (const float*)d_in[14];
    // d_in[15..22]: psi network + rho_attn — dead code (softmax shift-invariance)
    const float* W_k     = (const float*)d_in[23];
    const float* W_q     = (const float*)d_in[24];
    const float* rho_w1  = (const float*)d_in[25];
    const float* rho_b1  = (const float*)d_in[26];
    const float* rho_w2  = (const float*)d_in[27];
    const float* rho_b2  = (const float*)d_in[28];
    const float* rho_w3  = (const float*)d_in[29];
    const float* rho_b3  = (const float*)d_in[30];

    float*  ws       = (float*)d_ws;
    float*  demo_enc = ws;                    // 2048 floats
    float*  w_eff    = ws + 2048;             // 128 floats
    ushort* wT16     = (ushort*)(ws + 2176);  // 73728 ushorts = 36864 floats
    float*  partials = ws + 39040;            // 64*516 floats = 132 KB

    prep_all<<<449, 128, 0, stream>>>(demo, demo_w1, demo_b1, demo_w2, demo_b2,
                                      W_k, W_q, phi_w1, phi_w2, phi_w3,
                                      demo_enc, w_eff, wT16, partials);
    fused_main<<<NWG, 256, 0, stream>>>(
        times, values, meas, lengths, demo_enc, w_eff, wT16,
        phi_b1, phi_b2, phi_b3, partials);
    final_kernel<<<NB, 128, 0, stream>>>(partials, rho_w1, rho_b1, rho_w2, rho_b2,
                                         rho_w3, rho_b3, (float*)d_out);
}